// Round 6
// baseline (141.465 us; speedup 1.0000x reference)
//
#include <hip/hip_runtime.h>
#include <hip/hip_bf16.h>
#include <stdint.h>

#define NB    65536
#define FEATN 261
#define HIDN  128
#define NSTEP 17           // 17 MFMA k-steps of 16
#define SROW  296          // LDS A row stride in halfwords (16B-aligned)

#define ROWSG 128          // rows per gemm block
#define NTHRG 512

typedef __attribute__((ext_vector_type(8)))  short bf16x8;   // 8 bf16 = 4 VGPRs
typedef __attribute__((ext_vector_type(16))) float f32x16;   // 32x32 accum
typedef float f32x4u __attribute__((ext_vector_type(4), aligned(4)));  // dword-aligned float4

#define MFMA32(A, B, C) __builtin_amdgcn_mfma_f32_32x32x16_bf16(A, B, C, 0, 0, 0)

// ---------- pre-kernel: pack Wc1 into MFMA B-fragment order in d_ws ----------
// piece p = s*4 + nt (17*4 pieces, 1024 B each). lane l: n = nt*32 + (l&31),
// k = 16s + 8*(l>>5) + j, zero-padded past k=260.
__global__ void prep_B(const float* __restrict__ Wc1, uint16_t* __restrict__ wsB) {
    int t = blockIdx.x * blockDim.x + threadIdx.x;
    if (t >= NSTEP * 4 * 64) return;
    int p = t >> 6, l = t & 63;
    int s = p >> 2, nt = p & 3;
    int n = nt * 32 + (l & 31);
    int kb = 16 * s + 8 * (l >> 5);
    uint16_t hw[8];
    #pragma unroll
    for (int j = 0; j < 8; ++j) {
        int k = kb + j;
        float v = (k < FEATN) ? Wc1[(size_t)k * HIDN + n] : 0.f;
        __hip_bfloat16 b = __float2bfloat16(v);
        hw[j] = *reinterpret_cast<uint16_t*>(&b);
    }
    *reinterpret_cast<uint4*>(wsB + (size_t)p * 512 + l * 8) =
        *reinterpret_cast<uint4*>(hw);
}

// ---------- tree kernel: 16 rows/block, 16 lanes/row, no LDS ----------
__global__ void tree_kernel(
    const float* __restrict__ x,
    const float* __restrict__ w0, const float* __restrict__ b0,
    const float* __restrict__ w1, const float* __restrict__ b1,
    const float* __restrict__ w2, const float* __restrict__ b2,
    const float* __restrict__ leaf,
    float* __restrict__ out_p)
{
    const int tid = threadIdx.x;
    const int s   = tid & 15;
    const int row = blockIdx.x * 16 + (tid >> 4);
    const float* xr = x + (size_t)row * FEATN;

    // ---- register-preload all weights (uniform per 16-lane group) ----
    f32x4u w0q[4];
    #pragma unroll
    for (int j = 0; j < 4; ++j)
        w0q[j] = *reinterpret_cast<const f32x4u*>(w0 + 4 * s + 64 * j);
    const float w0t = (s < 5) ? w0[256 + s] : 0.f;

    f32x4u w1aq[2], w1bq[2];
    #pragma unroll
    for (int j = 0; j < 2; ++j) {
        w1aq[j] = *reinterpret_cast<const f32x4u*>(w1 + 5 + 8 * s + 4 * j);
        w1bq[j] = *reinterpret_cast<const f32x4u*>(w1 + 133 + 5 + 8 * s + 4 * j);
    }
    const float w1a5 = (s < 5) ? w1[s]       : 0.f;
    const float w1b5 = (s < 5) ? w1[133 + s] : 0.f;

    f32x4u w2q0 = *reinterpret_cast<const f32x4u*>(w2 +  0 * 69 + 5 + 4 * s);
    f32x4u w2q1 = *reinterpret_cast<const f32x4u*>(w2 +  1 * 69 + 5 + 4 * s);
    f32x4u w2q2 = *reinterpret_cast<const f32x4u*>(w2 +  2 * 69 + 5 + 4 * s);
    f32x4u w2q3 = *reinterpret_cast<const f32x4u*>(w2 +  3 * 69 + 5 + 4 * s);
    float w25_0 = (s < 5) ? w2[0 * 69 + s] : 0.f;
    float w25_1 = (s < 5) ? w2[1 * 69 + s] : 0.f;
    float w25_2 = (s < 5) ? w2[2 * 69 + s] : 0.f;
    float w25_3 = (s < 5) ? w2[3 * 69 + s] : 0.f;

    // ---- x loads for level 0 (4 dwordx4 + 2 scalars) ----
    f32x4u xq[4];
    #pragma unroll
    for (int j = 0; j < 4; ++j)
        xq[j] = *reinterpret_cast<const f32x4u*>(xr + 4 * s + 64 * j);
    const float xt  = (s < 5) ? xr[256 + s] : 0.f;
    const float xs5 = (s < 5) ? xr[s]       : 0.f;

    // ---- level 0 ----
    float part = xt * w0t;
    #pragma unroll
    for (int j = 0; j < 4; ++j)
        #pragma unroll
        for (int c = 0; c < 4; ++c)
            part += xq[j][c] * w0q[j][c];
    part += __shfl_xor(part, 1);
    part += __shfl_xor(part, 2);
    part += __shfl_xor(part, 4);
    part += __shfl_xor(part, 8);
    float gate = part + b0[0];
    int node = (gate >= 0.f) ? 1 : 0;
    float cum = 1.f / (1.f + __expf(-gate));

    // ---- level 1 ----
    {
        const float* base = xr + 5 + 128 * node + 8 * s;
        f32x4u xw0 = *reinterpret_cast<const f32x4u*>(base);
        f32x4u xw1 = *reinterpret_cast<const f32x4u*>(base + 4);
        part = xs5 * (node ? w1b5 : w1a5);
        #pragma unroll
        for (int c = 0; c < 4; ++c) {
            part += xw0[c] * (node ? w1bq[0][c] : w1aq[0][c]);
            part += xw1[c] * (node ? w1bq[1][c] : w1aq[1][c]);
        }
        part += __shfl_xor(part, 1);
        part += __shfl_xor(part, 2);
        part += __shfl_xor(part, 4);
        part += __shfl_xor(part, 8);
        gate = part + b1[node];
        cum *= 1.f / (1.f + __expf(-gate));
        node = node * 2 + ((gate >= 0.f) ? 1 : 0);
    }
    // ---- level 2 ----
    {
        f32x4u xv2 = *reinterpret_cast<const f32x4u*>(xr + 5 + 64 * node + 4 * s);
        f32x4u t0 = (node & 1) ? w2q1 : w2q0;
        f32x4u t1 = (node & 1) ? w2q3 : w2q2;
        f32x4u wsel = (node & 2) ? t1 : t0;
        float w5a = (node & 1) ? w25_1 : w25_0;
        float w5b = (node & 1) ? w25_3 : w25_2;
        float w5sel = (node & 2) ? w5b : w5a;
        part = xs5 * w5sel;
        #pragma unroll
        for (int c = 0; c < 4; ++c) part += xv2[c] * wsel[c];
        part += __shfl_xor(part, 1);
        part += __shfl_xor(part, 2);
        part += __shfl_xor(part, 4);
        part += __shfl_xor(part, 8);
        gate = part + b2[node];
        cum *= 1.f / (1.f + __expf(-gate));
        node = node * 2 + ((gate >= 0.f) ? 1 : 0);
    }
    if (s < 8)
        out_p[(size_t)row * 8 + s] = cum * leaf[node * 8 + s];
}

// ---------- critic GEMM kernel: 128 rows/block, 512 threads ----------
__global__ __launch_bounds__(NTHRG, 4) void critic_gemm(
    const float* __restrict__ x,
    const uint16_t* __restrict__ wsB,
    const float* __restrict__ bc1, const float* __restrict__ Wc2,
    const float* __restrict__ bc2,
    float* __restrict__ out_v)
{
    __shared__ uint16_t Axs[ROWSG * SROW];     // 75776 B
    __shared__ float bc1s[HIDN];
    __shared__ float wc2s[HIDN];
    __shared__ float vpart[ROWSG * 2];

    const int tid = threadIdx.x;
    const int rowBase = blockIdx.x * ROWSG;

    if (tid < HIDN) { bc1s[tid] = bc1[tid]; wc2s[tid] = Wc2[tid]; }
    if (tid < ROWSG) {                          // zero k = 261..295 pad
        uint16_t* rp = Axs + tid * SROW;
        rp[261] = 0;
        *reinterpret_cast<uint32_t*>(rp + 262) = 0u;
        uint4 z; z.x = z.y = z.z = z.w = 0u;
        *reinterpret_cast<uint4*>(rp + 264) = z;
        *reinterpret_cast<uint4*>(rp + 272) = z;
        *reinterpret_cast<uint4*>(rp + 280) = z;
        *reinterpret_cast<uint4*>(rp + 288) = z;
    }

    // ---- stage: coalesced float4 x read -> bf16 -> row-major LDS ----
    {
        const float4* xg4 = reinterpret_cast<const float4*>(x + (size_t)rowBase * FEATN);
        for (int i = tid; i < ROWSG * FEATN / 4; i += NTHRG) {
            float4 v = xg4[i];
            const float* vv = reinterpret_cast<const float*>(&v);
            int f = i << 2;
            int m = f / FEATN;          // magic-div
            int k = f - m * FEATN;
            if (k + 3 < FEATN) {        // fast path: single row
                uint16_t* dst = Axs + m * SROW + k;
                #pragma unroll
                for (int j = 0; j < 4; ++j) {
                    __hip_bfloat16 b = __float2bfloat16(vv[j]);
                    dst[j] = *reinterpret_cast<uint16_t*>(&b);
                }
            } else {
                #pragma unroll
                for (int j = 0; j < 4; ++j) {
                    if (k >= FEATN) { k -= FEATN; m++; }
                    __hip_bfloat16 b = __float2bfloat16(vv[j]);
                    Axs[m * SROW + k] = *reinterpret_cast<uint16_t*>(&b);
                    k++;
                }
            }
        }
    }
    __syncthreads();

    // ---- MFMA K-loop: A from LDS (b128), B from global frag-order;
    //      2-step groups, prefetch next group while MFMA current. ----
    const int lane = tid & 63;
    const int w    = tid >> 6;          // wave 0..7
    const int mt   = w >> 1;            // m-tile 0..3
    const int nh   = w & 1;             // n-tiles {2nh, 2nh+1}

    f32x16 acc0 = {}, acc1 = {};
    const uint16_t* arow = Axs + (mt * 32 + (lane & 31)) * SROW + (lane >> 5) * 8;
    const uint16_t* bgl  = wsB + (size_t)(2 * nh) * 512 + lane * 8;

    bf16x8 ca[2], cb0[2], cb1[2], na[2], nb0[2], nb1[2];
    #pragma unroll
    for (int d = 0; d < 2; ++d) {
        ca[d]  = *reinterpret_cast<const bf16x8*>(arow + d * 16);
        cb0[d] = *reinterpret_cast<const bf16x8*>(bgl + (size_t)(d * 4)     * 512);
        cb1[d] = *reinterpret_cast<const bf16x8*>(bgl + (size_t)(d * 4 + 1) * 512);
    }
    #pragma unroll
    for (int g = 0; g < 8; ++g) {
        if (g < 7) {
            #pragma unroll
            for (int d = 0; d < 2; ++d) {
                const int st = 2 * g + 2 + d;
                na[d]  = *reinterpret_cast<const bf16x8*>(arow + st * 16);
                nb0[d] = *reinterpret_cast<const bf16x8*>(bgl + (size_t)(st * 4)     * 512);
                nb1[d] = *reinterpret_cast<const bf16x8*>(bgl + (size_t)(st * 4 + 1) * 512);
            }
        } else {
            na[0]  = *reinterpret_cast<const bf16x8*>(arow + 16 * 16);
            nb0[0] = *reinterpret_cast<const bf16x8*>(bgl + (size_t)(16 * 4)     * 512);
            nb1[0] = *reinterpret_cast<const bf16x8*>(bgl + (size_t)(16 * 4 + 1) * 512);
        }
        #pragma unroll
        for (int d = 0; d < 2; ++d) {
            acc0 = MFMA32(ca[d], cb0[d], acc0);
            acc1 = MFMA32(ca[d], cb1[d], acc1);
        }
        #pragma unroll
        for (int d = 0; d < 2; ++d) { ca[d] = na[d]; cb0[d] = nb0[d]; cb1[d] = nb1[d]; }
    }
    acc0 = MFMA32(ca[0], cb0[0], acc0);   // tail step s = 16
    acc1 = MFMA32(ca[0], cb1[0], acc1);

    // ---- epilogue: bias+relu+Wc2 dot, cross-lane reduce, v write ----
    {
        const int c = lane & 31;
        const int q = lane >> 5;
        const int n0 = 2 * nh * 32 + c;
        const int n1 = n0 + 32;
        const float bb0 = bc1s[n0], ww0 = wc2s[n0];
        const float bb1 = bc1s[n1], ww1 = wc2s[n1];

        float pv[16];
        #pragma unroll
        for (int reg = 0; reg < 16; ++reg) {
            float h0 = acc0[reg] + bb0; h0 = h0 > 0.f ? h0 : 0.f;
            float h1 = acc1[reg] + bb1; h1 = h1 > 0.f ? h1 : 0.f;
            float t = h0 * ww0 + h1 * ww1;
            t += __shfl_xor(t, 1);
            t += __shfl_xor(t, 2);
            t += __shfl_xor(t, 4);
            t += __shfl_xor(t, 8);
            t += __shfl_xor(t, 16);
            pv[reg] = t;
        }
        #pragma unroll
        for (int reg = 0; reg < 16; ++reg) {
            if (c == reg) {
                int row_local = (reg & 3) + 8 * (reg >> 2) + 4 * q;
                vpart[(mt * 32 + row_local) * 2 + nh] = pv[reg];
            }
        }
    }
    __syncthreads();
    if (tid < ROWSG)
        out_v[rowBase + tid] = vpart[tid * 2] + vpart[tid * 2 + 1] + bc2[0];
}

extern "C" void kernel_launch(void* const* d_in, const int* in_sizes, int n_in,
                              void* d_out, int out_size, void* d_ws, size_t ws_size,
                              hipStream_t stream) {
    const float* x    = (const float*)d_in[0];
    const float* w0   = (const float*)d_in[1];
    const float* b0   = (const float*)d_in[2];
    const float* w1   = (const float*)d_in[3];
    const float* b1   = (const float*)d_in[4];
    const float* w2   = (const float*)d_in[5];
    const float* b2   = (const float*)d_in[6];
    const float* leaf = (const float*)d_in[7];
    const float* Wc1  = (const float*)d_in[8];
    const float* bc1  = (const float*)d_in[9];
    const float* Wc2  = (const float*)d_in[10];
    const float* bc2  = (const float*)d_in[11];

    uint16_t* wsB = (uint16_t*)d_ws;     // 17*4*1024 = 69632 B, frag order

    float* out_p = (float*)d_out;
    float* out_v = out_p + (size_t)NB * 8;

    prep_B<<<(NSTEP * 4 * 64 + 255) / 256, 256, 0, stream>>>(Wc1, wsB);
    tree_kernel<<<NB / 16, 256, 0, stream>>>(
        x, w0, b0, w1, b1, w2, b2, leaf, out_p);
    critic_gemm<<<NB / ROWSG, NTHRG, 0, stream>>>(
        x, wsB, bc1, Wc2, bc2, out_v);
}

// Round 7
// 137.658 us; speedup vs baseline: 1.0277x; 1.0277x over previous
//
#include <hip/hip_runtime.h>
#include <hip/hip_bf16.h>
#include <stdint.h>

#define NB    65536
#define FEATN 261
#define HIDN  128
#define NSTEP 17           // 17 MFMA k-steps of 16
#define SROW  296          // LDS A row stride in halfwords (rows 16B-aligned)

#define ROWSG 128          // rows per gemm block
#define NTHRG 512

typedef __attribute__((ext_vector_type(8)))  short bf16x8;   // 8 bf16 = 4 VGPRs
typedef __attribute__((ext_vector_type(16))) float f32x16;   // 32x32 accum
typedef float f32x4u __attribute__((ext_vector_type(4), aligned(4)));  // dword-aligned float4

#define MFMA32(A, B, C) __builtin_amdgcn_mfma_f32_32x32x16_bf16(A, B, C, 0, 0, 0)

__device__ __forceinline__ uint16_t f2b(float v) {
    __hip_bfloat16 b = __float2bfloat16(v);
    return *reinterpret_cast<uint16_t*>(&b);
}

// ---------- tree kernel: 16 rows/block, 16 lanes/row, no LDS ----------
// Blocks 0..16 additionally pack Wc1 into MFMA B-fragment order in d_ws
// (consumed by critic_gemm, which launches after us on the same stream).
__global__ void tree_kernel(
    const float* __restrict__ x,
    const float* __restrict__ w0, const float* __restrict__ b0,
    const float* __restrict__ w1, const float* __restrict__ b1,
    const float* __restrict__ w2, const float* __restrict__ b2,
    const float* __restrict__ leaf,
    const float* __restrict__ Wc1, uint16_t* __restrict__ wsB,
    float* __restrict__ out_p)
{
    const int tid = threadIdx.x;

    // ---- folded prep_B: piece p = s*4+nt; lane l: n = nt*32+(l&31),
    //      k = 16s + 8*(l>>5) + j, zero-padded past k=260 ----
    if (blockIdx.x < 17) {
        int t = blockIdx.x * 256 + tid;
        if (t < NSTEP * 4 * 64) {
            int p = t >> 6, l = t & 63;
            int s = p >> 2, nt = p & 3;
            int n = nt * 32 + (l & 31);
            int kb = 16 * s + 8 * (l >> 5);
            uint16_t hw[8];
            #pragma unroll
            for (int j = 0; j < 8; ++j) {
                int k = kb + j;
                float v = (k < FEATN) ? Wc1[(size_t)k * HIDN + n] : 0.f;
                hw[j] = f2b(v);
            }
            *reinterpret_cast<uint4*>(wsB + (size_t)p * 512 + l * 8) =
                *reinterpret_cast<uint4*>(hw);
        }
    }

    const int s   = tid & 15;
    const int row = blockIdx.x * 16 + (tid >> 4);
    const float* xr = x + (size_t)row * FEATN;

    // ---- register-preload all weights (uniform per 16-lane group) ----
    f32x4u w0q[4];
    #pragma unroll
    for (int j = 0; j < 4; ++j)
        w0q[j] = *reinterpret_cast<const f32x4u*>(w0 + 4 * s + 64 * j);
    const float w0t = (s < 5) ? w0[256 + s] : 0.f;

    f32x4u w1aq[2], w1bq[2];
    #pragma unroll
    for (int j = 0; j < 2; ++j) {
        w1aq[j] = *reinterpret_cast<const f32x4u*>(w1 + 5 + 8 * s + 4 * j);
        w1bq[j] = *reinterpret_cast<const f32x4u*>(w1 + 133 + 5 + 8 * s + 4 * j);
    }
    const float w1a5 = (s < 5) ? w1[s]       : 0.f;
    const float w1b5 = (s < 5) ? w1[133 + s] : 0.f;

    f32x4u w2q0 = *reinterpret_cast<const f32x4u*>(w2 +  0 * 69 + 5 + 4 * s);
    f32x4u w2q1 = *reinterpret_cast<const f32x4u*>(w2 +  1 * 69 + 5 + 4 * s);
    f32x4u w2q2 = *reinterpret_cast<const f32x4u*>(w2 +  2 * 69 + 5 + 4 * s);
    f32x4u w2q3 = *reinterpret_cast<const f32x4u*>(w2 +  3 * 69 + 5 + 4 * s);
    float w25_0 = (s < 5) ? w2[0 * 69 + s] : 0.f;
    float w25_1 = (s < 5) ? w2[1 * 69 + s] : 0.f;
    float w25_2 = (s < 5) ? w2[2 * 69 + s] : 0.f;
    float w25_3 = (s < 5) ? w2[3 * 69 + s] : 0.f;

    // ---- x loads for level 0 (4 dwordx4 + 2 scalars) ----
    f32x4u xq[4];
    #pragma unroll
    for (int j = 0; j < 4; ++j)
        xq[j] = *reinterpret_cast<const f32x4u*>(xr + 4 * s + 64 * j);
    const float xt  = (s < 5) ? xr[256 + s] : 0.f;
    const float xs5 = (s < 5) ? xr[s]       : 0.f;

    // ---- level 0 ----
    float part = xt * w0t;
    #pragma unroll
    for (int j = 0; j < 4; ++j)
        #pragma unroll
        for (int c = 0; c < 4; ++c)
            part += xq[j][c] * w0q[j][c];
    part += __shfl_xor(part, 1);
    part += __shfl_xor(part, 2);
    part += __shfl_xor(part, 4);
    part += __shfl_xor(part, 8);
    float gate = part + b0[0];
    int node = (gate >= 0.f) ? 1 : 0;
    float cum = 1.f / (1.f + __expf(-gate));

    // ---- level 1 (x reload is L1-hot: same row just read) ----
    {
        const float* base = xr + 5 + 128 * node + 8 * s;
        f32x4u xw0 = *reinterpret_cast<const f32x4u*>(base);
        f32x4u xw1 = *reinterpret_cast<const f32x4u*>(base + 4);
        part = xs5 * (node ? w1b5 : w1a5);
        #pragma unroll
        for (int c = 0; c < 4; ++c) {
            part += xw0[c] * (node ? w1bq[0][c] : w1aq[0][c]);
            part += xw1[c] * (node ? w1bq[1][c] : w1aq[1][c]);
        }
        part += __shfl_xor(part, 1);
        part += __shfl_xor(part, 2);
        part += __shfl_xor(part, 4);
        part += __shfl_xor(part, 8);
        gate = part + b1[node];
        cum *= 1.f / (1.f + __expf(-gate));
        node = node * 2 + ((gate >= 0.f) ? 1 : 0);
    }
    // ---- level 2 ----
    {
        f32x4u xv2 = *reinterpret_cast<const f32x4u*>(xr + 5 + 64 * node + 4 * s);
        f32x4u t0 = (node & 1) ? w2q1 : w2q0;
        f32x4u t1 = (node & 1) ? w2q3 : w2q2;
        f32x4u wsel = (node & 2) ? t1 : t0;
        float w5a = (node & 1) ? w25_1 : w25_0;
        float w5b = (node & 1) ? w25_3 : w25_2;
        float w5sel = (node & 2) ? w5b : w5a;
        part = xs5 * w5sel;
        #pragma unroll
        for (int c = 0; c < 4; ++c) part += xv2[c] * wsel[c];
        part += __shfl_xor(part, 1);
        part += __shfl_xor(part, 2);
        part += __shfl_xor(part, 4);
        part += __shfl_xor(part, 8);
        gate = part + b2[node];
        cum *= 1.f / (1.f + __expf(-gate));
        node = node * 2 + ((gate >= 0.f) ? 1 : 0);
    }
    if (s < 8)
        out_p[(size_t)row * 8 + s] = cum * leaf[node * 8 + s];
}

// ---------- critic GEMM kernel: 128 rows/block, 512 threads ----------
__global__ __launch_bounds__(NTHRG, 2) void critic_gemm(
    const float* __restrict__ x,
    const uint16_t* __restrict__ wsB,
    const float* __restrict__ bc1, const float* __restrict__ Wc2,
    const float* __restrict__ bc2,
    float* __restrict__ out_v)
{
    __shared__ uint16_t Axs[ROWSG * SROW];     // 75776 B
    __shared__ float bc1s[HIDN];
    __shared__ float wc2s[HIDN];
    __shared__ float vpart[ROWSG * 2];

    const int tid = threadIdx.x;
    const int rowBase = blockIdx.x * ROWSG;

    if (tid < HIDN) { bc1s[tid] = bc1[tid]; wc2s[tid] = Wc2[tid]; }
    if (tid < ROWSG) {                          // zero k = 261..295 pad
        uint16_t* rp = Axs + tid * SROW;
        rp[261] = 0;
        *reinterpret_cast<uint32_t*>(rp + 262) = 0u;
        uint4 z; z.x = z.y = z.z = z.w = 0u;
        *reinterpret_cast<uint4*>(rp + 264) = z;
        *reinterpret_cast<uint4*>(rp + 272) = z;
        *reinterpret_cast<uint4*>(rp + 280) = z;
        *reinterpret_cast<uint4*>(rp + 288) = z;
    }

    // ---- stage: (row,seg) indexed; seg = 4 floats -> one ds_write_b64 of
    //      4 packed bf16 (always 8B-aligned since rows are 16B-aligned). ----
    {
        for (int idx = tid; idx < ROWSG * 66; idx += NTHRG) {
            int row = idx / 66;            // magic-div
            int seg = idx - row * 66;
            const float* src = x + (size_t)(rowBase + row) * FEATN + 4 * seg;
            uint16_t* dst = Axs + row * SROW + 4 * seg;
            if (seg < 65) {
                f32x4u v = *reinterpret_cast<const f32x4u*>(src);
                uint32_t p0 = (uint32_t)f2b(v[0]) | ((uint32_t)f2b(v[1]) << 16);
                uint32_t p1 = (uint32_t)f2b(v[2]) | ((uint32_t)f2b(v[3]) << 16);
                uint2 pk; pk.x = p0; pk.y = p1;
                *reinterpret_cast<uint2*>(dst) = pk;   // ds_write_b64
            } else {
                dst[0] = f2b(src[0]);                  // k = 260 only
            }
        }
    }
    __syncthreads();

    // ---- K-loop: preload ALL fragments (A from LDS, B from L2-hot global)
    //      then 34 MFMAs on two independent accumulator chains. ----
    const int lane = tid & 63;
    const int w    = tid >> 6;          // wave 0..7
    const int mt   = w >> 1;            // m-tile 0..3
    const int nh   = w & 1;             // n-tiles {2nh, 2nh+1}

    const uint16_t* arow = Axs + (mt * 32 + (lane & 31)) * SROW + (lane >> 5) * 8;
    const uint16_t* bgl  = wsB + (size_t)(2 * nh) * 512 + lane * 8;

    bf16x8 af[NSTEP], bf0[NSTEP], bf1[NSTEP];
    #pragma unroll
    for (int s = 0; s < NSTEP; ++s) {
        af[s]  = *reinterpret_cast<const bf16x8*>(arow + s * 16);
        bf0[s] = *reinterpret_cast<const bf16x8*>(bgl + (size_t)(s * 4)     * 512);
        bf1[s] = *reinterpret_cast<const bf16x8*>(bgl + (size_t)(s * 4 + 1) * 512);
    }

    f32x16 acc0 = {}, acc1 = {};
    #pragma unroll
    for (int s = 0; s < NSTEP; ++s) {
        acc0 = MFMA32(af[s], bf0[s], acc0);
        acc1 = MFMA32(af[s], bf1[s], acc1);
    }

    // ---- epilogue: bias+relu+Wc2 dot, cross-lane reduce, v write ----
    {
        const int c = lane & 31;
        const int q = lane >> 5;
        const int n0 = 2 * nh * 32 + c;
        const int n1 = n0 + 32;
        const float bb0 = bc1s[n0], ww0 = wc2s[n0];
        const float bb1 = bc1s[n1], ww1 = wc2s[n1];

        float pv[16];
        #pragma unroll
        for (int reg = 0; reg < 16; ++reg) {
            float h0 = acc0[reg] + bb0; h0 = h0 > 0.f ? h0 : 0.f;
            float h1 = acc1[reg] + bb1; h1 = h1 > 0.f ? h1 : 0.f;
            float t = h0 * ww0 + h1 * ww1;
            t += __shfl_xor(t, 1);
            t += __shfl_xor(t, 2);
            t += __shfl_xor(t, 4);
            t += __shfl_xor(t, 8);
            t += __shfl_xor(t, 16);
            pv[reg] = t;
        }
        #pragma unroll
        for (int reg = 0; reg < 16; ++reg) {
            if (c == reg) {
                int row_local = (reg & 3) + 8 * (reg >> 2) + 4 * q;
                vpart[(mt * 32 + row_local) * 2 + nh] = pv[reg];
            }
        }
    }
    __syncthreads();
    if (tid < ROWSG)
        out_v[rowBase + tid] = vpart[tid * 2] + vpart[tid * 2 + 1] + bc2[0];
}

extern "C" void kernel_launch(void* const* d_in, const int* in_sizes, int n_in,
                              void* d_out, int out_size, void* d_ws, size_t ws_size,
                              hipStream_t stream) {
    const float* x    = (const float*)d_in[0];
    const float* w0   = (const float*)d_in[1];
    const float* b0   = (const float*)d_in[2];
    const float* w1   = (const float*)d_in[3];
    const float* b1   = (const float*)d_in[4];
    const float* w2   = (const float*)d_in[5];
    const float* b2   = (const float*)d_in[6];
    const float* leaf = (const float*)d_in[7];
    const float* Wc1  = (const float*)d_in[8];
    const float* bc1  = (const float*)d_in[9];
    const float* Wc2  = (const float*)d_in[10];
    const float* bc2  = (const float*)d_in[11];

    uint16_t* wsB = (uint16_t*)d_ws;     // 17*4*1024 = 69632 B, frag order

    float* out_p = (float*)d_out;
    float* out_v = out_p + (size_t)NB * 8;

    tree_kernel<<<NB / 16, 256, 0, stream>>>(
        x, w0, b0, w1, b1, w2, b2, leaf, Wc1, wsB, out_p);
    critic_gemm<<<NB / ROWSG, NTHRG, 0, stream>>>(
        x, wsB, bc1, Wc2, bc2, out_v);
}